// Round 1
// baseline (143.901 us; speedup 1.0000x reference)
//
#include <hip/hip_runtime.h>
#include <math.h>

#define CCH 64
#define HWN 1296
#define TS 216
#define TT 6
#define NTHREADS 256

#if defined(__has_builtin)
#  if __has_builtin(__builtin_amdgcn_exp2f)
#    define FAST_EXP2(x) __builtin_amdgcn_exp2f(x)
#  else
#    define FAST_EXP2(x) __expf((x) * 0.69314718055994531f)
#  endif
#else
#  define FAST_EXP2(x) __expf((x) * 0.69314718055994531f)
#endif

// ---------------- Kernel 1: 1x1-conv projections q,k,v,yproj ----------------
// grid = CCH*4 blocks; block b: c = b>>2, quad = b&3 covers 324 pixels.
__global__ __launch_bounds__(NTHREADS) void proj_kernel(
    const float* __restrict__ x, const float* __restrict__ y,
    const float* __restrict__ Wq, const float* __restrict__ bq,
    const float* __restrict__ Wk, const float* __restrict__ bk,
    const float* __restrict__ Wv, const float* __restrict__ bv,
    const float* __restrict__ Wp,
    float* __restrict__ q, float* __restrict__ k,
    float* __restrict__ v, float* __restrict__ yp)
{
    __shared__ float wq[CCH], wk[CCH], wv[CCH], wp[CCH];
    const int b = blockIdx.x;
    const int c = b >> 2;
    const int quad = b & 3;
    const int tid = threadIdx.x;
    if (tid < CCH) {
        wq[tid] = Wq[c * CCH + tid];
        wk[tid] = Wk[c * CCH + tid];
        wv[tid] = Wv[c * CCH + tid];
        wp[tid] = Wp[c * CCH + tid];
    }
    __syncthreads();
    const float bqc = bq[c], bkc = bk[c], bvc = bv[c];
    const int PQ = HWN / 4;  // 324
    for (int po = tid; po < PQ; po += NTHREADS) {
        const int p = quad * PQ + po;
        float aq = bqc, ak = bkc, av = bvc, ap = 0.f;
        #pragma unroll 8
        for (int i = 0; i < CCH; ++i) {
            const float xi = x[i * HWN + p];
            const float yi = y[i * HWN + p];
            aq = fmaf(wq[i], xi, aq);
            ak = fmaf(wk[i], xi, ak);
            av = fmaf(wv[i], yi, av);
            ap = fmaf(wp[i], yi, ap);
        }
        q[c * HWN + p]  = aq;
        k[c * HWN + p]  = ak;
        v[c * HWN + p]  = av;
        yp[c * HWN + p] = ap;
    }
}

// ---------------- Kernel 2: rank-1 attention + gated residual ----------------
// grid = CCH*TT blocks; block: c = bx/TT, tile t = bx%TT covers i in [t*216, t*216+216)
__global__ __launch_bounds__(NTHREADS) void att_kernel(
    const float* __restrict__ q, const float* __restrict__ k,
    const float* __restrict__ v, const float* __restrict__ yp,
    const float* __restrict__ gamma, float* __restrict__ out)
{
    __shared__ __align__(16) float ks[HWN];
    __shared__ __align__(16) float vs[HWN];
    __shared__ float swmax[4], swmin[4];
    __shared__ float skmax, skmin;
    const int c = blockIdx.x / TT;
    const int t = blockIdx.x % TT;
    const int tid = threadIdx.x;

    float lmax = -1e30f, lmin = 1e30f;
    for (int j = tid; j < HWN; j += NTHREADS) {
        const float kv = k[c * HWN + j];
        ks[j] = kv;
        vs[j] = v[c * HWN + j];
        lmax = fmaxf(lmax, kv);
        lmin = fminf(lmin, kv);
    }
    #pragma unroll
    for (int off = 32; off > 0; off >>= 1) {
        lmax = fmaxf(lmax, __shfl_xor(lmax, off, 64));
        lmin = fminf(lmin, __shfl_xor(lmin, off, 64));
    }
    const int wave = tid >> 6;
    if ((tid & 63) == 0) { swmax[wave] = lmax; swmin[wave] = lmin; }
    __syncthreads();
    if (tid == 0) {
        skmax = fmaxf(fmaxf(swmax[0], swmax[1]), fmaxf(swmax[2], swmax[3]));
        skmin = fminf(fminf(swmin[0], swmin[1]), fminf(swmin[2], swmin[3]));
    }
    __syncthreads();

    if (tid < TS) {
        const int i = t * TS + tid;
        const float L2E = 1.4426950408889634f;
        const float a2 = q[c * HWN + i] * L2E;           // logits scaled to exp2 domain
        const float m2 = (a2 >= 0.f) ? a2 * skmax : a2 * skmin;  // exact row max
        float se = 0.f, sev = 0.f;
        const float4* k4 = (const float4*)ks;
        const float4* v4 = (const float4*)vs;
        #pragma unroll 2
        for (int jj = 0; jj < HWN / 4; ++jj) {
            const float4 kk = k4[jj];   // LDS broadcast (all lanes same addr)
            const float4 vv = v4[jj];
            const float e0 = FAST_EXP2(fmaf(a2, kk.x, -m2));
            const float e1 = FAST_EXP2(fmaf(a2, kk.y, -m2));
            const float e2 = FAST_EXP2(fmaf(a2, kk.z, -m2));
            const float e3 = FAST_EXP2(fmaf(a2, kk.w, -m2));
            se += (e0 + e1) + (e2 + e3);
            sev = fmaf(e0, vv.x, sev);
            sev = fmaf(e1, vv.y, sev);
            sev = fmaf(e2, vv.z, sev);
            sev = fmaf(e3, vv.w, sev);
        }
        const float g = gamma[0];
        const float att = sev / se;
        out[c * HWN + i] = (g * att + yp[c * HWN + i]) / (1.f + g);
    }
}

// ---------------- Fallback: fully fused (only if ws too small) ----------------
__global__ __launch_bounds__(NTHREADS) void fused_kernel(
    const float* __restrict__ x, const float* __restrict__ y,
    const float* __restrict__ Wq, const float* __restrict__ bq,
    const float* __restrict__ Wk, const float* __restrict__ bk,
    const float* __restrict__ Wv, const float* __restrict__ bv,
    const float* __restrict__ Wp, const float* __restrict__ gamma,
    float* __restrict__ out)
{
    __shared__ __align__(16) float ks[HWN];
    __shared__ __align__(16) float vs[HWN];
    __shared__ float wq[CCH], wk[CCH], wv[CCH], wp[CCH];
    __shared__ float qs[TS], yps[TS];
    __shared__ float swmax[4], swmin[4];
    __shared__ float skmax, skmin;
    const int c = blockIdx.x / TT;
    const int t = blockIdx.x % TT;
    const int tid = threadIdx.x;

    if (tid < CCH) {
        wq[tid] = Wq[c * CCH + tid];
        wk[tid] = Wk[c * CCH + tid];
        wv[tid] = Wv[c * CCH + tid];
        wp[tid] = Wp[c * CCH + tid];
    }
    __syncthreads();
    const float bkc = bk[c], bvc = bv[c], bqc = bq[c];

    float lmax = -1e30f, lmin = 1e30f;
    for (int j = tid; j < HWN; j += NTHREADS) {
        float ak = bkc, av = bvc;
        #pragma unroll 8
        for (int i = 0; i < CCH; ++i) {
            ak = fmaf(wk[i], x[i * HWN + j], ak);
            av = fmaf(wv[i], y[i * HWN + j], av);
        }
        ks[j] = ak; vs[j] = av;
        lmax = fmaxf(lmax, ak);
        lmin = fminf(lmin, ak);
    }
    for (int ii = tid; ii < TS; ii += NTHREADS) {
        const int p = t * TS + ii;
        float aq = bqc, ap = 0.f;
        #pragma unroll 8
        for (int i = 0; i < CCH; ++i) {
            aq = fmaf(wq[i], x[i * HWN + p], aq);
            ap = fmaf(wp[i], y[i * HWN + p], ap);
        }
        qs[ii] = aq; yps[ii] = ap;
    }
    #pragma unroll
    for (int off = 32; off > 0; off >>= 1) {
        lmax = fmaxf(lmax, __shfl_xor(lmax, off, 64));
        lmin = fminf(lmin, __shfl_xor(lmin, off, 64));
    }
    const int wave = tid >> 6;
    if ((tid & 63) == 0) { swmax[wave] = lmax; swmin[wave] = lmin; }
    __syncthreads();
    if (tid == 0) {
        skmax = fmaxf(fmaxf(swmax[0], swmax[1]), fmaxf(swmax[2], swmax[3]));
        skmin = fminf(fminf(swmin[0], swmin[1]), fminf(swmin[2], swmin[3]));
    }
    __syncthreads();

    if (tid < TS) {
        const int i = t * TS + tid;
        const float L2E = 1.4426950408889634f;
        const float a2 = qs[tid] * L2E;
        const float m2 = (a2 >= 0.f) ? a2 * skmax : a2 * skmin;
        float se = 0.f, sev = 0.f;
        const float4* k4 = (const float4*)ks;
        const float4* v4 = (const float4*)vs;
        #pragma unroll 2
        for (int jj = 0; jj < HWN / 4; ++jj) {
            const float4 kk = k4[jj];
            const float4 vv = v4[jj];
            const float e0 = FAST_EXP2(fmaf(a2, kk.x, -m2));
            const float e1 = FAST_EXP2(fmaf(a2, kk.y, -m2));
            const float e2 = FAST_EXP2(fmaf(a2, kk.z, -m2));
            const float e3 = FAST_EXP2(fmaf(a2, kk.w, -m2));
            se += (e0 + e1) + (e2 + e3);
            sev = fmaf(e0, vv.x, sev);
            sev = fmaf(e1, vv.y, sev);
            sev = fmaf(e2, vv.z, sev);
            sev = fmaf(e3, vv.w, sev);
        }
        const float g = gamma[0];
        const float att = sev / se;
        out[c * HWN + i] = (g * att + yps[tid]) / (1.f + g);
    }
}

extern "C" void kernel_launch(void* const* d_in, const int* in_sizes, int n_in,
                              void* d_out, int out_size, void* d_ws, size_t ws_size,
                              hipStream_t stream) {
    (void)in_sizes; (void)n_in; (void)out_size;
    const float* x  = (const float*)d_in[0];
    const float* y  = (const float*)d_in[1];
    const float* Wq = (const float*)d_in[2];
    const float* bq = (const float*)d_in[3];
    const float* Wk = (const float*)d_in[4];
    const float* bk = (const float*)d_in[5];
    const float* Wv = (const float*)d_in[6];
    const float* bv = (const float*)d_in[7];
    const float* Wp = (const float*)d_in[8];
    const float* gamma = (const float*)d_in[9];
    float* out = (float*)d_out;

    const size_t need = (size_t)4 * CCH * HWN * sizeof(float);
    if (ws_size >= need) {
        float* q  = (float*)d_ws;
        float* k  = q + CCH * HWN;
        float* v  = k + CCH * HWN;
        float* yp = v + CCH * HWN;
        proj_kernel<<<CCH * 4, NTHREADS, 0, stream>>>(x, y, Wq, bq, Wk, bk, Wv, bv, Wp,
                                                      q, k, v, yp);
        att_kernel<<<CCH * TT, NTHREADS, 0, stream>>>(q, k, v, yp, gamma, out);
    } else {
        fused_kernel<<<CCH * TT, NTHREADS, 0, stream>>>(x, y, Wq, bq, Wk, bk, Wv, bv, Wp,
                                                        gamma, out);
    }
}

// Round 2
// 93.278 us; speedup vs baseline: 1.5427x; 1.5427x over previous
//
#include <hip/hip_runtime.h>
#include <math.h>

#define CCH 64
#define HWN 1296
#define NTHREADS 256
#define NTILES 21          // ceil(1296/64) i-tiles per channel in att2
#define TS 216
#define TT 6

#if defined(__has_builtin)
#  if __has_builtin(__builtin_amdgcn_exp2f)
#    define FAST_EXP2(x) __builtin_amdgcn_exp2f(x)
#  else
#    define FAST_EXP2(x) __expf((x) * 0.69314718055994531f)
#  endif
#else
#  define FAST_EXP2(x) __expf((x) * 0.69314718055994531f)
#endif

// ---------------- Kernel 1: 1x1-conv projections q,k,v,yproj ----------------
// 648 blocks: b<324 -> x-part (q,k), else y-part (v,yp).
// Thread = one (c,p) pair; idx = c*1296+p so the output store is out[idx].
// Weights for the (at most 2) channels the block touches staged in LDS.
// x/y column loads done in explicit 16-deep batches to force 16 loads in
// flight (R0 post-mortem: VGPR=32 build had ~2 in flight -> 470 cyc/load).
__global__ __launch_bounds__(NTHREADS) void proj2(
    const float* __restrict__ x, const float* __restrict__ y,
    const float* __restrict__ Wq, const float* __restrict__ bq,
    const float* __restrict__ Wk, const float* __restrict__ bk,
    const float* __restrict__ Wv, const float* __restrict__ bv,
    const float* __restrict__ Wp,
    float* __restrict__ q, float* __restrict__ k,
    float* __restrict__ v, float* __restrict__ yp)
{
    __shared__ float wsA[2][CCH], wsB[2][CCH];
    const int b = blockIdx.x;
    const bool xpart = (b < 324);
    const int bb = xpart ? b : b - 324;
    const int tid = threadIdx.x;
    const int idx = bb * NTHREADS + tid;     // 0..82943 = c*1296+p
    const int c = idx / HWN;
    const int p = idx - c * HWN;
    const int c0 = (bb * NTHREADS) / HWN;
    const int c1 = (bb * NTHREADS + NTHREADS - 1) / HWN;

    // stage weight rows c0,c1 for the two matrices this part needs
    {
        const int i6 = tid & 63;
        const int rsel = (tid >> 6) & 1;
        const int msel = tid >> 7;
        const int crow = rsel ? c1 : c0;
        const float* WA = xpart ? Wq : Wv;
        const float* WB = xpart ? Wk : Wp;
        if (msel == 0) wsA[rsel][i6] = WA[crow * CCH + i6];
        else           wsB[rsel][i6] = WB[crow * CCH + i6];
    }
    __syncthreads();

    const int rs = (c == c0) ? 0 : 1;
    const float* wA = wsA[rs];
    const float* wB = wsB[rs];
    float accA = xpart ? bq[c] : bv[c];
    float accB = xpart ? bk[c] : 0.f;
    const float* src = xpart ? x : y;
    const float* col = src + p;

    #pragma unroll
    for (int u = 0; u < CCH; u += 16) {
        float xv[16];
        #pragma unroll
        for (int t = 0; t < 16; ++t) xv[t] = col[(u + t) * HWN];
        #pragma unroll
        for (int t = 0; t < 16; ++t) {
            accA = fmaf(wA[u + t], xv[t], accA);
            accB = fmaf(wB[u + t], xv[t], accB);
        }
    }
    if (xpart) { q[idx] = accA; k[idx] = accB; }
    else       { v[idx] = accA; yp[idx] = accB; }
}

// ---------------- Kernel 2: rank-1 attention + gated residual ----------------
// grid = 64 ch * 21 i-tiles. Block: 64 i's (one per lane), j-loop split
// across the 4 waves (324 j each), cross-wave reduce in LDS.
__global__ __launch_bounds__(NTHREADS) void att2(
    const float* __restrict__ q, const float* __restrict__ k,
    const float* __restrict__ v, const float* __restrict__ yp,
    const float* __restrict__ gamma, float* __restrict__ out)
{
    __shared__ __align__(16) float4 k4[HWN / 4];
    __shared__ __align__(16) float4 v4[HWN / 4];
    __shared__ float sse[4][64], ssev[4][64];
    __shared__ float swmax[4], swmin[4];
    const int c = blockIdx.x / NTILES;
    const int itile = blockIdx.x % NTILES;
    const int tid = threadIdx.x;
    const int w = tid >> 6;
    const int l = tid & 63;

    const float4* kg = (const float4*)(k + c * HWN);
    const float4* vg = (const float4*)(v + c * HWN);
    float lmax = -1e30f, lmin = 1e30f;
    for (int j = tid; j < HWN / 4; j += NTHREADS) {
        const float4 kk = kg[j];
        k4[j] = kk;
        v4[j] = vg[j];
        lmax = fmaxf(fmaxf(lmax, kk.x), fmaxf(kk.y, fmaxf(kk.z, kk.w)));
        lmin = fminf(fminf(lmin, kk.x), fminf(kk.y, fminf(kk.z, kk.w)));
    }
    #pragma unroll
    for (int off = 32; off > 0; off >>= 1) {
        lmax = fmaxf(lmax, __shfl_xor(lmax, off, 64));
        lmin = fminf(lmin, __shfl_xor(lmin, off, 64));
    }
    if (l == 0) { swmax[w] = lmax; swmin[w] = lmin; }
    __syncthreads();
    const float kmax = fmaxf(fmaxf(swmax[0], swmax[1]), fmaxf(swmax[2], swmax[3]));
    const float kmin = fminf(fminf(swmin[0], swmin[1]), fminf(swmin[2], swmin[3]));

    const int i = itile * 64 + l;
    const int iv = (i < HWN) ? i : (HWN - 1);
    const float L2E = 1.4426950408889634f;
    const float a2 = q[c * HWN + iv] * L2E;
    const float m2 = (a2 >= 0.f) ? a2 * kmax : a2 * kmin;   // exact row max (rank-1)
    float se = 0.f, sev = 0.f;
    const int j0 = w * 81;
    #pragma unroll 3
    for (int jj = 0; jj < 81; ++jj) {
        const float4 kk = k4[j0 + jj];   // all lanes same addr -> LDS broadcast
        const float4 vv = v4[j0 + jj];
        const float e0 = FAST_EXP2(fmaf(a2, kk.x, -m2));
        const float e1 = FAST_EXP2(fmaf(a2, kk.y, -m2));
        const float e2 = FAST_EXP2(fmaf(a2, kk.z, -m2));
        const float e3 = FAST_EXP2(fmaf(a2, kk.w, -m2));
        se += (e0 + e1) + (e2 + e3);
        sev = fmaf(e0, vv.x, sev);
        sev = fmaf(e1, vv.y, sev);
        sev = fmaf(e2, vv.z, sev);
        sev = fmaf(e3, vv.w, sev);
    }
    sse[w][l] = se;
    ssev[w][l] = sev;
    __syncthreads();
    if (tid < 64) {
        const int io = itile * 64 + tid;
        if (io < HWN) {
            const float seT  = (sse[0][tid] + sse[1][tid]) + (sse[2][tid] + sse[3][tid]);
            const float sevT = (ssev[0][tid] + ssev[1][tid]) + (ssev[2][tid] + ssev[3][tid]);
            const float g = gamma[0];
            out[c * HWN + io] = (g * (sevT / seT) + yp[c * HWN + io]) / (1.f + g);
        }
    }
}

// ---------------- Fallback: fully fused (only if ws too small) ----------------
__global__ __launch_bounds__(NTHREADS) void fused_kernel(
    const float* __restrict__ x, const float* __restrict__ y,
    const float* __restrict__ Wq, const float* __restrict__ bq,
    const float* __restrict__ Wk, const float* __restrict__ bk,
    const float* __restrict__ Wv, const float* __restrict__ bv,
    const float* __restrict__ Wp, const float* __restrict__ gamma,
    float* __restrict__ out)
{
    __shared__ __align__(16) float ks[HWN];
    __shared__ __align__(16) float vs[HWN];
    __shared__ float wq[CCH], wk[CCH], wv[CCH], wp[CCH];
    __shared__ float qs[TS], yps[TS];
    __shared__ float swmax[4], swmin[4];
    __shared__ float skmax, skmin;
    const int c = blockIdx.x / TT;
    const int t = blockIdx.x % TT;
    const int tid = threadIdx.x;

    if (tid < CCH) {
        wq[tid] = Wq[c * CCH + tid];
        wk[tid] = Wk[c * CCH + tid];
        wv[tid] = Wv[c * CCH + tid];
        wp[tid] = Wp[c * CCH + tid];
    }
    __syncthreads();
    const float bkc = bk[c], bvc = bv[c], bqc = bq[c];

    float lmax = -1e30f, lmin = 1e30f;
    for (int j = tid; j < HWN; j += NTHREADS) {
        float ak = bkc, av = bvc;
        #pragma unroll 8
        for (int i = 0; i < CCH; ++i) {
            ak = fmaf(wk[i], x[i * HWN + j], ak);
            av = fmaf(wv[i], y[i * HWN + j], av);
        }
        ks[j] = ak; vs[j] = av;
        lmax = fmaxf(lmax, ak);
        lmin = fminf(lmin, ak);
    }
    for (int ii = tid; ii < TS; ii += NTHREADS) {
        const int p = t * TS + ii;
        float aq = bqc, ap = 0.f;
        #pragma unroll 8
        for (int i = 0; i < CCH; ++i) {
            aq = fmaf(wq[i], x[i * HWN + p], aq);
            ap = fmaf(wp[i], y[i * HWN + p], ap);
        }
        qs[ii] = aq; yps[ii] = ap;
    }
    #pragma unroll
    for (int off = 32; off > 0; off >>= 1) {
        lmax = fmaxf(lmax, __shfl_xor(lmax, off, 64));
        lmin = fminf(lmin, __shfl_xor(lmin, off, 64));
    }
    const int wave = tid >> 6;
    if ((tid & 63) == 0) { swmax[wave] = lmax; swmin[wave] = lmin; }
    __syncthreads();
    if (tid == 0) {
        skmax = fmaxf(fmaxf(swmax[0], swmax[1]), fmaxf(swmax[2], swmax[3]));
        skmin = fminf(fminf(swmin[0], swmin[1]), fminf(swmin[2], swmin[3]));
    }
    __syncthreads();

    if (tid < TS) {
        const int i = t * TS + tid;
        const float L2E = 1.4426950408889634f;
        const float a2 = qs[tid] * L2E;
        const float m2 = (a2 >= 0.f) ? a2 * skmax : a2 * skmin;
        float se = 0.f, sev = 0.f;
        const float4* k4 = (const float4*)ks;
        const float4* v4 = (const float4*)vs;
        #pragma unroll 2
        for (int jj = 0; jj < HWN / 4; ++jj) {
            const float4 kk = k4[jj];
            const float4 vv = v4[jj];
            const float e0 = FAST_EXP2(fmaf(a2, kk.x, -m2));
            const float e1 = FAST_EXP2(fmaf(a2, kk.y, -m2));
            const float e2 = FAST_EXP2(fmaf(a2, kk.z, -m2));
            const float e3 = FAST_EXP2(fmaf(a2, kk.w, -m2));
            se += (e0 + e1) + (e2 + e3);
            sev = fmaf(e0, vv.x, sev);
            sev = fmaf(e1, vv.y, sev);
            sev = fmaf(e2, vv.z, sev);
            sev = fmaf(e3, vv.w, sev);
        }
        const float g = gamma[0];
        const float att = sev / se;
        out[c * HWN + i] = (g * att + yps[tid]) / (1.f + g);
    }
}

extern "C" void kernel_launch(void* const* d_in, const int* in_sizes, int n_in,
                              void* d_out, int out_size, void* d_ws, size_t ws_size,
                              hipStream_t stream) {
    (void)in_sizes; (void)n_in; (void)out_size;
    const float* x  = (const float*)d_in[0];
    const float* y  = (const float*)d_in[1];
    const float* Wq = (const float*)d_in[2];
    const float* bq = (const float*)d_in[3];
    const float* Wk = (const float*)d_in[4];
    const float* bk = (const float*)d_in[5];
    const float* Wv = (const float*)d_in[6];
    const float* bv = (const float*)d_in[7];
    const float* Wp = (const float*)d_in[8];
    const float* gamma = (const float*)d_in[9];
    float* out = (float*)d_out;

    const size_t need = (size_t)4 * CCH * HWN * sizeof(float);
    if (ws_size >= need) {
        float* q  = (float*)d_ws;
        float* k  = q + CCH * HWN;
        float* v  = k + CCH * HWN;
        float* yp = v + CCH * HWN;
        proj2<<<648, NTHREADS, 0, stream>>>(x, y, Wq, bq, Wk, bk, Wv, bv, Wp,
                                            q, k, v, yp);
        att2<<<CCH * NTILES, NTHREADS, 0, stream>>>(q, k, v, yp, gamma, out);
    } else {
        fused_kernel<<<CCH * TT, NTHREADS, 0, stream>>>(x, y, Wq, bq, Wk, bk, Wv, bv, Wp,
                                                        gamma, out);
    }
}